// Round 6
// baseline (112.245 us; speedup 1.0000x reference)
//
#include <hip/hip_runtime.h>
#include <math.h>

#define NOBS 45
typedef float2 c32;

// wire -> storage-bit map: w0,w1 local (bits 1,0); w2..w7 lane bits 5,4,3,1,0,2 (storage 7,6,5,3,2,4); w8,w9 wave (9,8)
// Precomputed storage-bit tables for the 45 observable pairs (PA_s = bit of wire a, PB_s = bit of wire b)
__device__ __constant__ int PA_s[NOBS] = {
    1,1,1,1,1,1,1,1,1, 0,0,0,0,0,0,0,0, 7,7,7,7,7,7,7, 6,6,6,6,6,6,
    5,5,5,5,5, 3,3,3,3, 2,2,2, 4,4, 9};
__device__ __constant__ int PB_s[NOBS] = {
    0,7,6,5,3,2,4,9,8, 7,6,5,3,2,4,9,8, 6,5,3,2,4,9,8, 5,3,2,4,9,8,
    3,2,4,9,8, 2,4,9,8, 4,9,8, 9,8, 8};
constexpr int TIc[6] = {1, 2, 2, 3, 3, 3};
constexpr int TJc[6] = {0, 0, 1, 0, 1, 2};

__device__ __forceinline__ c32 cfma(c32 a, c32 b, c32 c) {
    c.x = fmaf(a.x, b.x, fmaf(-a.y, b.y, c.x));
    c.y = fmaf(a.x, b.y, fmaf(a.y, b.x, c.y));
    return c;
}
__device__ __forceinline__ c32 cmul(c32 a, c32 b) {
    return make_float2(a.x * b.x - a.y * b.y, a.x * b.y + a.y * b.x);
}

// ---------------- cross-lane exchange on the VALU pipe ----------------
template <int CTRL>
__device__ __forceinline__ float dppf(float x) {
    return __uint_as_float((unsigned)__builtin_amdgcn_update_dpp(
        0, (int)__float_as_uint(x), CTRL, 0xF, 0xF, true));
}
// lane^32 via v_permlane32_swap; sum-minus-self is convention-immune (HW-validated r2-r5)
__device__ __forceinline__ float swap32f(float a) {
    auto r = __builtin_amdgcn_permlane32_swap(__float_as_uint(a), __float_as_uint(a), false, false);
    return (__uint_as_float(r[0]) + __uint_as_float(r[1])) - a;
}
#if __has_builtin(__builtin_amdgcn_permlane16_swap)
__device__ __forceinline__ float swap16f(float a) {
    auto r = __builtin_amdgcn_permlane16_swap(__float_as_uint(a), __float_as_uint(a), false, false);
    return (__uint_as_float(r[0]) + __uint_as_float(r[1])) - a;
}
#else
__device__ __forceinline__ float swap16f(float a) { return __shfl_xor(a, 16, 64); }
#endif
__device__ __forceinline__ float swz4f(float a) {  // lane^4 via ds_swizzle
    return __uint_as_float(__builtin_amdgcn_ds_swizzle(__float_as_uint(a), 0x101F));
}
template <int M>
__device__ __forceinline__ float exf(float x) {
    float r = x;
    if constexpr ((M & 3) == 1) r = dppf<0xB1>(r);        // quad_perm [1,0,3,2]
    else if constexpr ((M & 3) == 2) r = dppf<0x4E>(r);   // quad_perm [2,3,0,1]
    else if constexpr ((M & 3) == 3) r = dppf<0x1B>(r);   // quad_perm [3,2,1,0]
    if constexpr (M & 4)  r = swz4f(r);
    if constexpr (M & 8)  r = dppf<0x128>(r);             // row_ror:8 == lane^8 (within 16)
    if constexpr (M & 16) r = swap16f(r);
    if constexpr (M & 32) r = swap32f(r);
    return r;
}
template <int M>
__device__ __forceinline__ c32 exch(c32 a) { return make_float2(exf<M>(a.x), exf<M>(a.y)); }
__device__ __forceinline__ c32 swap32c(c32 a) { return make_float2(swap32f(a.x), swap32f(a.y)); }

// full-wave sum via DPP adds; total lands in lane 63
__device__ __forceinline__ float wave_reduce63(float x) {
    x += dppf<0x111>(x);  // row_shr:1
    x += dppf<0x112>(x);  // row_shr:2
    x += dppf<0x114>(x);  // row_shr:4
    x += dppf<0x118>(x);  // row_shr:8
    x += dppf<0x142>(x);  // row_bcast15
    x += dppf<0x143>(x);  // row_bcast31
    return x;
}

__device__ __forceinline__ int insert2(int t, int pl, int ph) {
    int low  = t & ((1 << pl) - 1);
    int rest = t >> pl;
    int nm   = ph - 1 - pl;
    int mid  = rest & ((1 << nm) - 1);
    int high = rest >> nm;
    return low | (mid << (pl + 1)) | (high << (ph + 1));
}

// Pauli 2x2 entry, word W in {0=I,1=X,2=Y,3=Z}
template <int W>
__device__ __forceinline__ c32 pE(int r, int c) {
    if constexpr (W == 0) return make_float2((r == c) ? 1.f : 0.f, 0.f);
    else if constexpr (W == 1) return make_float2((r != c) ? 1.f : 0.f, 0.f);
    else if constexpr (W == 2) return make_float2(0.f, (r == c) ? 0.f : ((r == 0) ? -1.f : 1.f));
    else return make_float2((r == c) ? ((r == 0) ? 1.f : -1.f) : 0.f, 0.f);
}
template <int W0, int W1>
__device__ __forceinline__ void paccum(c32& H, float th, int i1, int i2, int j1, int j2) {
    c32 a = pE<W0>(i1, j1), b = pE<W1>(i2, j2);
    c32 p = cmul(a, b);
    H.x = fmaf(th, p.x, H.x);
    H.y = fmaf(th, p.y, H.y);
}

// ---------- gate fragments ----------
struct F16 { c32 u[16]; };
struct FLoc { c32 a[4]; c32 b[4]; };
struct F4 { c32 uS, uB, uA, uC; };

__device__ __forceinline__ F16 loadF16(const c32* __restrict__ U) {
    F16 f;
#pragma unroll
    for (int i = 0; i < 16; i++) f.u[i] = U[i];
    return f;
}
__device__ __forceinline__ FLoc loadLoc(const c32* __restrict__ U, int ln) {
    int bb = (ln >> 5) & 1;
    const c32* U0 = U + bb * 4;
    const c32* U1 = U + (2 | bb) * 4;
    int c00 = bb, c01 = 2 | bb, c10 = bb ^ 1, c11 = 2 | (bb ^ 1);
    FLoc f;
    f.a[0] = U0[c00]; f.a[1] = U0[c01]; f.a[2] = U0[c10]; f.a[3] = U0[c11];
    f.b[0] = U1[c00]; f.b[1] = U1[c01]; f.b[2] = U1[c10]; f.b[3] = U1[c11];
    return f;
}
template <int QA, int QB>
__device__ __forceinline__ F4 loadL2(const c32* __restrict__ U, int ln) {
    int bA = (ln >> QA) & 1, bB = (ln >> QB) & 1;
    int r = (bA << 1) | bB;
    const c32* Ur = U + r * 4;
    F4 f;
    f.uS = Ur[r]; f.uB = Ur[r ^ 1]; f.uA = Ur[r ^ 2]; f.uC = Ur[r ^ 3];
    return f;
}

__device__ __forceinline__ void applyLL(c32 v[4], const F16& f) {
    c32 n0 = cfma(f.u[0],  v[0], cfma(f.u[1],  v[1], cfma(f.u[2],  v[2], cmul(f.u[3],  v[3]))));
    c32 n1 = cfma(f.u[4],  v[0], cfma(f.u[5],  v[1], cfma(f.u[6],  v[2], cmul(f.u[7],  v[3]))));
    c32 n2 = cfma(f.u[8],  v[0], cfma(f.u[9],  v[1], cfma(f.u[10], v[2], cmul(f.u[11], v[3]))));
    c32 n3 = cfma(f.u[12], v[0], cfma(f.u[13], v[1], cfma(f.u[14], v[2], cmul(f.u[15], v[3]))));
    v[0] = n0; v[1] = n1; v[2] = n2; v[3] = n3;
}
__device__ __forceinline__ void applyLoc(c32 v[4], const FLoc& f) {
    c32 p0 = swap32c(v[0]), p1 = swap32c(v[1]), p2 = swap32c(v[2]), p3 = swap32c(v[3]);
    c32 n0 = cfma(f.a[0], v[0], cfma(f.a[1], v[1], cfma(f.a[2], p0, cmul(f.a[3], p1))));
    c32 n1 = cfma(f.b[0], v[0], cfma(f.b[1], v[1], cfma(f.b[2], p0, cmul(f.b[3], p1))));
    c32 n2 = cfma(f.a[0], v[2], cfma(f.a[1], v[3], cfma(f.a[2], p2, cmul(f.a[3], p3))));
    c32 n3 = cfma(f.b[0], v[2], cfma(f.b[1], v[3], cfma(f.b[2], p2, cmul(f.b[3], p3))));
    v[0] = n0; v[1] = n1; v[2] = n2; v[3] = n3;
}
template <int QA, int QB>
__device__ __forceinline__ void applyL2(c32 v[4], const F4& f) {
#pragma unroll
    for (int lc = 0; lc < 4; lc++) {
        c32 pB = exch<(1 << QB)>(v[lc]);
        c32 pA = exch<(1 << QA)>(v[lc]);
        c32 pC = exch<(1 << QA)>(pB);
        v[lc] = cfma(f.uS, v[lc], cfma(f.uB, pB, cfma(f.uA, pA, cmul(f.uC, pC))));
    }
}

// ---------- flat psi storage ----------
__device__ __forceinline__ void dumpV(const c32 v[4], c32* __restrict__ psi, int t) {
#pragma unroll
    for (int lc = 0; lc < 4; lc++) psi[(t << 2) | lc] = v[lc];
}
__device__ __forceinline__ void loadV(c32 v[4], const c32* __restrict__ psi, int t) {
#pragma unroll
    for (int lc = 0; lc < 4; lc++) v[lc] = psi[(t << 2) | lc];
}
// LDS apply for wave-crossing bits. PA = wire a's bit, PB = wire b's bit.
template <int PA, int PB>
__device__ __forceinline__ void ldsApply(const F16& f, c32* __restrict__ psi, int t) {
    constexpr int PL = (PA < PB) ? PA : PB, PH = (PA < PB) ? PB : PA;
    int base = insert2(t, PL, PH);
    constexpr int oa = 1 << PA, ob = 1 << PB;
    c32 g0 = psi[base], g1 = psi[base + ob], g2 = psi[base + oa], g3 = psi[base + oa + ob];
    c32 n0 = cfma(f.u[0],  g0, cfma(f.u[1],  g1, cfma(f.u[2],  g2, cmul(f.u[3],  g3))));
    c32 n1 = cfma(f.u[4],  g0, cfma(f.u[5],  g1, cfma(f.u[6],  g2, cmul(f.u[7],  g3))));
    c32 n2 = cfma(f.u[8],  g0, cfma(f.u[9],  g1, cfma(f.u[10], g2, cmul(f.u[11], g3))));
    c32 n3 = cfma(f.u[12], g0, cfma(f.u[13], g1, cfma(f.u[14], g2, cmul(f.u[15], g3))));
    psi[base] = n0; psi[base + ob] = n1; psi[base + oa] = n2; psi[base + oa + ob] = n3;
}

__global__ __launch_bounds__(256, 1) void mega_kernel(
    const float* __restrict__ x,  const float* __restrict__ W1, const float* __restrict__ b1,
    const float* __restrict__ W2, const float* __restrict__ b2, const float* __restrict__ qp,
    const float* __restrict__ Am, const float* __restrict__ Bm, const float* __restrict__ Dm,
    float* __restrict__ out) {
    __shared__ __align__(16) c32 psiS[1024];  // scratch (MLP/expm/prep) then psi
    __shared__ c32 UeS[144];       // 9 encoding unitaries
    __shared__ c32 GpS[720];       // 45 fused pyramid gates
    __shared__ float HbS[720];     // 45 compact Hermitians: [2D0,2D1,2D2,pad, 6x(2A,2B)]
    __shared__ float encS[136];
    __shared__ float redS[180];

    const int b = blockIdx.x, t = threadIdx.x, ln = t & 63;
    float* F = (float*)psiS;  // 2048 floats of scratch

    // ================= Phase 1: MLP =================
    if (t < 128) ((float4*)F)[t] = ((const float4*)(x + (size_t)b * 512))[t];
    __syncthreads();
    {
        int q = t & 63, sl = t >> 6;
        float4 a4 = make_float4(0.f, 0.f, 0.f, 0.f);
#pragma unroll 16
        for (int kk = 0; kk < 128; kk++) {
            int k = sl * 128 + kk;
            float xk = F[k];
            const float4 w = *(const float4*)(W1 + (size_t)k * 256 + q * 4);
            a4.x = fmaf(xk, w.x, a4.x); a4.y = fmaf(xk, w.y, a4.y);
            a4.z = fmaf(xk, w.z, a4.z); a4.w = fmaf(xk, w.w, a4.w);
        }
        *(float4*)(F + 512 + sl * 256 + q * 4) = a4;
    }
    __syncthreads();
    {
        float hv = b1[t] + F[512 + t] + F[768 + t] + F[1024 + t] + F[1280 + t];
        hv = hv / (1.f + __expf(-hv));      // silu
        F[1536 + t] = hv;
    }
    __syncthreads();
    if (t < 135) {
        float a2 = b2[t], a3 = 0.f;
#pragma unroll 16
        for (int k = 0; k < 128; k++) {
            a2 = fmaf(F[1536 + k],       W2[(size_t)k * 135 + t],         a2);
            a3 = fmaf(F[1536 + 128 + k], W2[(size_t)(128 + k) * 135 + t], a3);
        }
        encS[t] = a2 + a3;
    }
    __syncthreads();

    // ========== Phase 2+3 merged: expm (t<144) | prep (144..233) | Hb (234..255) ==========
    // expm: exp(iH) = exp(iH/64)^64, Taylor deg 7
    c32* Mm = psiS;        // [0,144)
    c32* Rb = psiS + 144;  // [144,288)
    c32* TA = psiS + 288;  // [288,1008) prep ping; pong = GpS
    if (t < 144) {
        int m = t >> 4, e = t & 15, i = e >> 2, j = e & 3;
        int i1 = i >> 1, i2 = i & 1, j1 = j >> 1, j2 = j & 1;
        const float* th = encS + m * 15;
        c32 H = make_float2(0.f, 0.f);
        paccum<0,1>(H, th[0],  i1,i2,j1,j2); paccum<0,2>(H, th[1],  i1,i2,j1,j2);
        paccum<0,3>(H, th[2],  i1,i2,j1,j2); paccum<1,0>(H, th[3],  i1,i2,j1,j2);
        paccum<1,1>(H, th[4],  i1,i2,j1,j2); paccum<1,2>(H, th[5],  i1,i2,j1,j2);
        paccum<1,3>(H, th[6],  i1,i2,j1,j2); paccum<2,0>(H, th[7],  i1,i2,j1,j2);
        paccum<2,1>(H, th[8],  i1,i2,j1,j2); paccum<2,2>(H, th[9],  i1,i2,j1,j2);
        paccum<2,3>(H, th[10], i1,i2,j1,j2); paccum<3,0>(H, th[11], i1,i2,j1,j2);
        paccum<3,1>(H, th[12], i1,i2,j1,j2); paccum<3,2>(H, th[13], i1,i2,j1,j2);
        paccum<3,3>(H, th[14], i1,i2,j1,j2);
        const float sc = 1.f / 64.f;
        Mm[t] = make_float2(-H.y * sc, H.x * sc);                  // i*H/64
        Rb[t] = make_float2((i == j) ? 1.f : 0.f, 0.f);            // R = I
    } else if (t >= 234) {
        for (int w = t - 234; w < NOBS; w += 22) {
            float* Hf = HbS + w * 16;
            Hf[0] = 2.f * Dm[w * 4 + 1];
            Hf[1] = 2.f * Dm[w * 4 + 2];
            Hf[2] = 2.f * Dm[w * 4 + 3];
            Hf[3] = 0.f;
#pragma unroll
            for (int k = 0; k < 6; k++) {
                Hf[4 + 2 * k] = 2.f * Am[w * 6 + k];
                Hf[5 + 2 * k] = 2.f * Bm[w * 6 + k];
            }
        }
    }
    __syncthreads();
    c32 Mrow[4];
    if (t < 144) {
        int m = t >> 4, i = (t & 15) >> 2;
#pragma unroll
        for (int k = 0; k < 4; k++) Mrow[k] = Mm[m * 16 + i * 4 + k];
    }
#pragma unroll 1
    for (int step = 0; step < 13; step++) {   // expm: 7 Horner + 6 squarings; prep: steps 0..7
        if (t < 144) {
            int m = t >> 4, e = t & 15, i = e >> 2, j = e & 3;
            const c32* cur = (step & 1) ? UeS : Rb;
            c32 acc = make_float2(0.f, 0.f);
            c32 outv;
            if (step < 7) {
#pragma unroll
                for (int k = 0; k < 4; k++) acc = cfma(Mrow[k], cur[m * 16 + k * 4 + j], acc);
                float inv = 1.f / (float)(7 - step);
                outv = make_float2(fmaf(acc.x, inv, (i == j) ? 1.f : 0.f), acc.y * inv);
            } else {
#pragma unroll
                for (int k = 0; k < 4; k++)
                    acc = cfma(cur[m * 16 + i * 4 + k], cur[m * 16 + k * 4 + j], acc);
                outv = acc;
            }
            ((step & 1) ? Rb : UeS)[t] = outv;
        } else if (t >= 144 && t < 234 && step < 8) {
            int pt = t - 144, g = pt >> 1, ih = (pt & 1) << 1;
            const float* p = qp + g * 12;
            const c32* src = ((step & 1) ? TA : GpS) + g * 16;
            c32* dst = ((step & 1) ? GpS : TA) + g * 16;
#pragma unroll
            for (int r2 = 0; r2 < 2; r2++) {
                int i = ih + r2, i1 = i >> 1, i2 = i & 1;
                c32 row[4];
                if (step == 0) {
                    float s, c; __sincosf(p[0] * 0.5f, &s, &c);
                    c32 u0, u1;
                    if (i1 == 0) { u0 = make_float2(c, 0.f);
                                   u1 = make_float2(-__cosf(p[2]) * s, -__sinf(p[2]) * s); }
                    else { u0 = make_float2(__cosf(p[1]) * s, __sinf(p[1]) * s);
                           u1 = make_float2(__cosf(p[1] + p[2]) * c, __sinf(p[1] + p[2]) * c); }
#pragma unroll
                    for (int jj = 0; jj < 4; jj++) row[jj] = make_float2(0.f, 0.f);
                    row[i2] = u0; row[2 | i2] = u1;
                } else {
                    c32 coef0, coef1; int c0, c1;
                    if (step == 1 || step == 5) {              // XX
                        float s, c; __sincosf(p[step == 1 ? 3 : 9] * 0.5f, &s, &c);
                        c0 = i; coef0 = make_float2(c, 0.f);
                        c1 = i ^ 3; coef1 = make_float2(0.f, -s);
                    } else if (step == 2 || step == 6) {       // YY
                        float s, c; __sincosf(p[step == 2 ? 4 : 10] * 0.5f, &s, &c);
                        float yy = (i == 0 || i == 3) ? 1.f : -1.f;
                        c0 = i; coef0 = make_float2(c, 0.f);
                        c1 = i ^ 3; coef1 = make_float2(0.f, s * yy);
                    } else if (step == 3 || step == 7) {       // ZZ (diag)
                        float s, c; __sincosf(p[step == 3 ? 5 : 11] * 0.5f, &s, &c);
                        float zz = (i == 0 || i == 3) ? 1.f : -1.f;
                        c0 = i; coef0 = make_float2(c, -s * zz);
                        c1 = i; coef1 = make_float2(0.f, 0.f);
                    } else {                                    // step 4: U3b (high qubit)
                        float s, c; __sincosf(p[6] * 0.5f, &s, &c);
                        if (i1 == 0) { coef0 = make_float2(c, 0.f);
                                       coef1 = make_float2(-__cosf(p[8]) * s, -__sinf(p[8]) * s); }
                        else { coef0 = make_float2(__cosf(p[7]) * s, __sinf(p[7]) * s);
                               coef1 = make_float2(__cosf(p[7] + p[8]) * c, __sinf(p[7] + p[8]) * c); }
                        c0 = i2; c1 = 2 | i2;
                    }
#pragma unroll
                    for (int jj = 0; jj < 4; jj++)
                        row[jj] = cfma(coef0, src[c0 * 4 + jj], cmul(coef1, src[c1 * 4 + jj]));
                }
#pragma unroll
                for (int jj = 0; jj < 4; jj++) dst[i * 4 + jj] = row[jj];
            }
        }
        __syncthreads();
    }

    // ================= Phase 4: state-vector simulation (registers; ROLLED pyramid) =================
    c32 v[4];
#pragma unroll
    for (int lc = 0; lc < 4; lc++) v[lc] = make_float2(0.f, 0.f);
    if (t == 0) v[0] = make_float2(1.f, 0.f);

    // encoding brick layer: (0,1)(2,3)(4,5)(6,7)(8,9)(1,2)(3,4)(5,6)(7,8)
    applyLL(v, loadF16(UeS + 0));
    applyL2<5, 4>(v, loadL2<5, 4>(UeS + 16, ln));
    applyL2<3, 1>(v, loadL2<3, 1>(UeS + 32, ln));
    applyL2<0, 2>(v, loadL2<0, 2>(UeS + 48, ln));
    dumpV(v, psiS, t); __syncthreads();
    ldsApply<9, 8>(loadF16(UeS + 64), psiS, t); __syncthreads();
    loadV(v, psiS, t);
    applyLoc(v, loadLoc(UeS + 80, ln));
    applyL2<4, 3>(v, loadL2<4, 3>(UeS + 96, ln));
    applyL2<1, 0>(v, loadL2<1, 0>(UeS + 112, ln));
    dumpV(v, psiS, t); __syncthreads();
    ldsApply<4, 9>(loadF16(UeS + 128), psiS, t); __syncthreads();
    loadV(v, psiS, t);

    // pyramid: rolled layer loop — gate code emitted ONCE (I$-resident)
    {
        int g = 0;
#pragma unroll 1
        for (int layer = 0; layer < 9; layer++) {
            const int amax = 8 - layer;
            applyLL(v, loadF16(GpS + (g++) * 16));                              // (0,1)
            if (amax >= 1) applyLoc(v, loadLoc(GpS + (g++) * 16, ln));          // (1,2)
            if (amax >= 2) applyL2<5, 4>(v, loadL2<5, 4>(GpS + (g++) * 16, ln)); // (2,3)
            if (amax >= 3) applyL2<4, 3>(v, loadL2<4, 3>(GpS + (g++) * 16, ln)); // (3,4)
            if (amax >= 4) applyL2<3, 1>(v, loadL2<3, 1>(GpS + (g++) * 16, ln)); // (4,5)
            if (amax >= 5) applyL2<1, 0>(v, loadL2<1, 0>(GpS + (g++) * 16, ln)); // (5,6)
            if (amax >= 6) applyL2<0, 2>(v, loadL2<0, 2>(GpS + (g++) * 16, ln)); // (6,7)
            if (amax >= 7) {
                dumpV(v, psiS, t); __syncthreads();
                ldsApply<4, 9>(loadF16(GpS + (g++) * 16), psiS, t); __syncthreads();  // (7,8)
                if (amax >= 8) {
                    ldsApply<9, 8>(loadF16(GpS + (g++) * 16), psiS, t); __syncthreads();  // (8,9)
                }
                loadV(v, psiS, t);
            }
        }
    }

    // ================= Phase 5: observables (ROLLED groups, ILP x5, DPP reduce) =================
    dumpV(v, psiS, t);
    __syncthreads();
#pragma unroll 1
    for (int w0 = 0; w0 < NOBS; w0 += 5) {
        float pr[5];
#pragma unroll
        for (int u = 0; u < 5; u++) {
            const int w = w0 + u;
            const int pa = PA_s[w], pb = PB_s[w];
            const int pl = (pa < pb) ? pa : pb, phh = (pa < pb) ? pb : pa;
            const int oa = 1 << pa, ob = 1 << pb;
            int i0 = insert2(t, pl, phh);
            c32 vg[4];
            vg[0] = psiS[i0];      vg[1] = psiS[i0 + ob];
            vg[2] = psiS[i0 + oa]; vg[3] = psiS[i0 + oa + ob];
            const float* Hf = HbS + w * 16;
            float r = Hf[0] * fmaf(vg[0].x, vg[0].x, vg[0].y * vg[0].y)
                    + Hf[1] * fmaf(vg[1].x, vg[1].x, vg[1].y * vg[1].y)
                    + Hf[2] * fmaf(vg[2].x, vg[2].x, vg[2].y * vg[2].y);
#pragma unroll
            for (int k = 0; k < 6; k++) {
                c32 vi = vg[TIc[k]], vj = vg[TJc[k]];
                float cx = fmaf(vi.x, vj.x, vi.y * vj.y);
                float cy = fmaf(vi.x, vj.y, -vi.y * vj.x);
                r = fmaf(Hf[4 + 2 * k], cx, r);
                r = fmaf(-Hf[5 + 2 * k], cy, r);
            }
            pr[u] = wave_reduce63(r);
        }
        if (ln == 63) {
#pragma unroll
            for (int u = 0; u < 5; u++) redS[(w0 + u) * 4 + (t >> 6)] = pr[u];
        }
    }
    __syncthreads();
    if (t < NOBS)
        out[(size_t)b * NOBS + t] = redS[t * 4] + redS[t * 4 + 1] + redS[t * 4 + 2] + redS[t * 4 + 3];
}

extern "C" void kernel_launch(void* const* d_in, const int* in_sizes, int n_in,
                              void* d_out, int out_size, void* d_ws, size_t ws_size,
                              hipStream_t stream) {
    (void)in_sizes; (void)n_in; (void)out_size; (void)d_ws; (void)ws_size;
    const float* x  = (const float*)d_in[0];
    const float* W1 = (const float*)d_in[1];
    const float* b1 = (const float*)d_in[2];
    const float* W2 = (const float*)d_in[3];
    const float* b2 = (const float*)d_in[4];
    const float* qp = (const float*)d_in[5];
    const float* Am = (const float*)d_in[6];
    const float* Bm = (const float*)d_in[7];
    const float* Dm = (const float*)d_in[8];
    float* out = (float*)d_out;

    hipLaunchKernelGGL(mega_kernel, dim3(256), dim3(256), 0, stream,
                       x, W1, b1, W2, b2, qp, Am, Bm, Dm, out);
}

// Round 7
// 106.562 us; speedup vs baseline: 1.0533x; 1.0533x over previous
//
#include <hip/hip_runtime.h>
#include <math.h>

#define NOBS 45
typedef float2 c32;

// wire -> storage-bit map: w0,w1 local (bits 1,0); w2..w7 lane bits 5,4,3,1,0,2 (storage 7,6,5,3,2,4); w8,w9 wave (9,8)
constexpr int W2Sc[10] = {1, 0, 7, 6, 5, 3, 2, 4, 9, 8};
constexpr int OAc[NOBS] = {
    0,0,0,0,0,0,0,0,0, 1,1,1,1,1,1,1,1, 2,2,2,2,2,2,2, 3,3,3,3,3,3,
    4,4,4,4,4, 5,5,5,5, 6,6,6, 7,7, 8};
constexpr int OBc[NOBS] = {
    1,2,3,4,5,6,7,8,9, 2,3,4,5,6,7,8,9, 3,4,5,6,7,8,9, 4,5,6,7,8,9,
    5,6,7,8,9, 6,7,8,9, 7,8,9, 8,9, 9};
constexpr int TIc[6] = {1, 2, 2, 3, 3, 3};
constexpr int TJc[6] = {0, 0, 1, 0, 1, 2};

__device__ __forceinline__ c32 cfma(c32 a, c32 b, c32 c) {
    c.x = fmaf(a.x, b.x, fmaf(-a.y, b.y, c.x));
    c.y = fmaf(a.x, b.y, fmaf(a.y, b.x, c.y));
    return c;
}
__device__ __forceinline__ c32 cmul(c32 a, c32 b) {
    return make_float2(a.x * b.x - a.y * b.y, a.x * b.y + a.y * b.x);
}

// ---------------- cross-lane exchange on the VALU pipe ----------------
template <int CTRL>
__device__ __forceinline__ float dppf(float x) {
    return __uint_as_float((unsigned)__builtin_amdgcn_update_dpp(
        0, (int)__float_as_uint(x), CTRL, 0xF, 0xF, true));
}
// lane^32 via v_permlane32_swap; sum-minus-self is convention-immune (HW-validated r2-r6)
__device__ __forceinline__ float swap32f(float a) {
    auto r = __builtin_amdgcn_permlane32_swap(__float_as_uint(a), __float_as_uint(a), false, false);
    return (__uint_as_float(r[0]) + __uint_as_float(r[1])) - a;
}
#if __has_builtin(__builtin_amdgcn_permlane16_swap)
__device__ __forceinline__ float swap16f(float a) {
    auto r = __builtin_amdgcn_permlane16_swap(__float_as_uint(a), __float_as_uint(a), false, false);
    return (__uint_as_float(r[0]) + __uint_as_float(r[1])) - a;
}
#else
__device__ __forceinline__ float swap16f(float a) { return __shfl_xor(a, 16, 64); }
#endif
template <int OFF>
__device__ __forceinline__ float swzf(float a) {
    return __uint_as_float(__builtin_amdgcn_ds_swizzle(__float_as_uint(a), OFF));
}
template <int M>
__device__ __forceinline__ float exf(float x) {
    float r = x;
    if constexpr ((M & 3) == 1) r = dppf<0xB1>(r);        // quad_perm [1,0,3,2]
    else if constexpr ((M & 3) == 2) r = dppf<0x4E>(r);   // quad_perm [2,3,0,1]
    else if constexpr ((M & 3) == 3) r = dppf<0x1B>(r);   // quad_perm [3,2,1,0]
    if constexpr (M & 4)  r = swzf<0x101F>(r);            // lane^4 via ds_swizzle
    if constexpr (M & 8)  r = dppf<0x128>(r);             // row_ror:8 == lane^8 (within 16)
    if constexpr (M & 16) r = swap16f(r);
    if constexpr (M & 32) r = swap32f(r);
    return r;
}
template <int M>
__device__ __forceinline__ c32 exch(c32 a) { return make_float2(exf<M>(a.x), exf<M>(a.y)); }
__device__ __forceinline__ c32 swap32c(c32 a) { return make_float2(swap32f(a.x), swap32f(a.y)); }

// 4x4-matrix in-wave swizzles: lanes grouped 16/matrix, e = i*4+j on lane[3:0]
template <int K>
__device__ __forceinline__ c32 swzrow(c32 a) {  // fetch entry (i, K): keep bits[4],[3:2], set [1:0]=K
    constexpr int off = (K << 5) | 0x1C;
    return make_float2(swzf<off>(a.x), swzf<off>(a.y));
}
template <int K>
__device__ __forceinline__ c32 swzcol(c32 a) {  // fetch entry (K, j): keep bits[4],[1:0], set [3:2]=K
    constexpr int off = ((K << 2) << 5) | 0x13;
    return make_float2(swzf<off>(a.x), swzf<off>(a.y));
}

// full-wave sum via DPP adds; total lands in lane 63
__device__ __forceinline__ float wave_reduce63(float x) {
    x += dppf<0x111>(x);  // row_shr:1
    x += dppf<0x112>(x);  // row_shr:2
    x += dppf<0x114>(x);  // row_shr:4
    x += dppf<0x118>(x);  // row_shr:8
    x += dppf<0x142>(x);  // row_bcast15
    x += dppf<0x143>(x);  // row_bcast31
    return x;
}

__device__ __forceinline__ int insert2(int t, int pl, int ph) {
    int low  = t & ((1 << pl) - 1);
    int rest = t >> pl;
    int nm   = ph - 1 - pl;
    int mid  = rest & ((1 << nm) - 1);
    int high = rest >> nm;
    return low | (mid << (pl + 1)) | (high << (ph + 1));
}

// Pauli 2x2 entry, word W in {0=I,1=X,2=Y,3=Z}
template <int W>
__device__ __forceinline__ c32 pE(int r, int c) {
    if constexpr (W == 0) return make_float2((r == c) ? 1.f : 0.f, 0.f);
    else if constexpr (W == 1) return make_float2((r != c) ? 1.f : 0.f, 0.f);
    else if constexpr (W == 2) return make_float2(0.f, (r == c) ? 0.f : ((r == 0) ? -1.f : 1.f));
    else return make_float2((r == c) ? ((r == 0) ? 1.f : -1.f) : 0.f, 0.f);
}
template <int W0, int W1>
__device__ __forceinline__ void paccum(c32& H, float th, int i1, int i2, int j1, int j2) {
    c32 a = pE<W0>(i1, j1), b = pE<W1>(i2, j2);
    c32 p = cmul(a, b);
    H.x = fmaf(th, p.x, H.x);
    H.y = fmaf(th, p.y, H.y);
}

// ---------- per-thread pyramid-gate composition (registers only) ----------
__device__ __forceinline__ void buildU3kron(c32* d, float th, float ph, float la) {
    float s, c; __sincosf(th * 0.5f, &s, &c);
    c32 u00 = make_float2(c, 0.f);
    c32 u01 = make_float2(-__cosf(la) * s, -__sinf(la) * s);
    c32 u10 = make_float2(__cosf(ph) * s, __sinf(ph) * s);
    c32 u11 = make_float2(__cosf(ph + la) * c, __sinf(ph + la) * c);
#pragma unroll
    for (int i = 0; i < 16; i++) d[i] = make_float2(0.f, 0.f);
    d[0] = u00; d[2] = u01; d[5] = u00; d[7] = u01;
    d[8] = u10; d[10] = u11; d[13] = u10; d[15] = u11;
}
__device__ __forceinline__ void stepXX(c32* d, const c32* sM, float phi) {
    float s, c; __sincosf(phi * 0.5f, &s, &c);
    c32 k1 = make_float2(0.f, -s);
#pragma unroll
    for (int i = 0; i < 4; i++)
#pragma unroll
        for (int j = 0; j < 4; j++)
            d[i * 4 + j] = cfma(k1, sM[(i ^ 3) * 4 + j],
                                make_float2(c * sM[i * 4 + j].x, c * sM[i * 4 + j].y));
}
__device__ __forceinline__ void stepYY(c32* d, const c32* sM, float phi) {
    float s, c; __sincosf(phi * 0.5f, &s, &c);
#pragma unroll
    for (int i = 0; i < 4; i++) {
        float yy = (i == 0 || i == 3) ? 1.f : -1.f;
        c32 k1 = make_float2(0.f, s * yy);
#pragma unroll
        for (int j = 0; j < 4; j++)
            d[i * 4 + j] = cfma(k1, sM[(i ^ 3) * 4 + j],
                                make_float2(c * sM[i * 4 + j].x, c * sM[i * 4 + j].y));
    }
}
__device__ __forceinline__ void stepZZ(c32* d, const c32* sM, float phi) {
    float s, c; __sincosf(phi * 0.5f, &s, &c);
#pragma unroll
    for (int i = 0; i < 4; i++) {
        float zz = (i == 0 || i == 3) ? 1.f : -1.f;
        c32 k = make_float2(c, -s * zz);
#pragma unroll
        for (int j = 0; j < 4; j++) d[i * 4 + j] = cmul(k, sM[i * 4 + j]);
    }
}
__device__ __forceinline__ void stepU3(c32* d, const c32* sM, float th, float ph, float la) {
    float s, c; __sincosf(th * 0.5f, &s, &c);
    c32 u00 = make_float2(c, 0.f);
    c32 u01 = make_float2(-__cosf(la) * s, -__sinf(la) * s);
    c32 u10 = make_float2(__cosf(ph) * s, __sinf(ph) * s);
    c32 u11 = make_float2(__cosf(ph + la) * c, __sinf(ph + la) * c);
#pragma unroll
    for (int i = 0; i < 4; i++) {
        int i1 = i >> 1, i2 = i & 1;
        c32 c0 = i1 ? u10 : u00, c1 = i1 ? u11 : u01;
#pragma unroll
        for (int j = 0; j < 4; j++)
            d[i * 4 + j] = cfma(c0, sM[i2 * 4 + j], cmul(c1, sM[(2 | i2) * 4 + j]));
    }
}

// ---------- gate fragments ----------
struct F16 { c32 u[16]; };
struct FLoc { c32 a[4]; c32 b[4]; };
struct F4 { c32 uS, uB, uA, uC; };

__device__ __forceinline__ F16 loadF16(const c32* __restrict__ U) {
    F16 f;
#pragma unroll
    for (int i = 0; i < 16; i++) f.u[i] = U[i];
    return f;
}
__device__ __forceinline__ FLoc loadLoc(const c32* __restrict__ U, int ln) {
    int bb = (ln >> 5) & 1;
    const c32* U0 = U + bb * 4;
    const c32* U1 = U + (2 | bb) * 4;
    int c00 = bb, c01 = 2 | bb, c10 = bb ^ 1, c11 = 2 | (bb ^ 1);
    FLoc f;
    f.a[0] = U0[c00]; f.a[1] = U0[c01]; f.a[2] = U0[c10]; f.a[3] = U0[c11];
    f.b[0] = U1[c00]; f.b[1] = U1[c01]; f.b[2] = U1[c10]; f.b[3] = U1[c11];
    return f;
}
template <int QA, int QB>
__device__ __forceinline__ F4 loadL2(const c32* __restrict__ U, int ln) {
    int bA = (ln >> QA) & 1, bB = (ln >> QB) & 1;
    int r = (bA << 1) | bB;
    const c32* Ur = U + r * 4;
    F4 f;
    f.uS = Ur[r]; f.uB = Ur[r ^ 1]; f.uA = Ur[r ^ 2]; f.uC = Ur[r ^ 3];
    return f;
}

__device__ __forceinline__ void applyLL(c32 v[4], const F16& f) {
    c32 n0 = cfma(f.u[3],  v[3], cfma(f.u[2],  v[2], cfma(f.u[1],  v[1], cmul(f.u[0],  v[0]))));
    c32 n1 = cfma(f.u[7],  v[3], cfma(f.u[6],  v[2], cfma(f.u[5],  v[1], cmul(f.u[4],  v[0]))));
    c32 n2 = cfma(f.u[11], v[3], cfma(f.u[10], v[2], cfma(f.u[9],  v[1], cmul(f.u[8],  v[0]))));
    c32 n3 = cfma(f.u[15], v[3], cfma(f.u[14], v[2], cfma(f.u[13], v[1], cmul(f.u[12], v[0]))));
    v[0] = n0; v[1] = n1; v[2] = n2; v[3] = n3;
}
// batched exchanges, swapped operands consumed LAST in the chain
__device__ __forceinline__ void applyLoc(c32 v[4], const FLoc& f) {
    c32 p0 = swap32c(v[0]), p1 = swap32c(v[1]), p2 = swap32c(v[2]), p3 = swap32c(v[3]);
    c32 n0 = cfma(f.a[3], p1, cfma(f.a[2], p0, cfma(f.a[1], v[1], cmul(f.a[0], v[0]))));
    c32 n1 = cfma(f.b[3], p1, cfma(f.b[2], p0, cfma(f.b[1], v[1], cmul(f.b[0], v[0]))));
    c32 n2 = cfma(f.a[3], p3, cfma(f.a[2], p2, cfma(f.a[1], v[3], cmul(f.a[0], v[2]))));
    c32 n3 = cfma(f.b[3], p3, cfma(f.b[2], p2, cfma(f.b[1], v[3], cmul(f.b[0], v[2]))));
    v[0] = n0; v[1] = n1; v[2] = n2; v[3] = n3;
}
template <int QA, int QB>
__device__ __forceinline__ void applyL2(c32 v[4], const F4& f) {
    c32 pB[4], pA[4], pC[4];
#pragma unroll
    for (int lc = 0; lc < 4; lc++) pB[lc] = exch<(1 << QB)>(v[lc]);
#pragma unroll
    for (int lc = 0; lc < 4; lc++) pA[lc] = exch<(1 << QA)>(v[lc]);
#pragma unroll
    for (int lc = 0; lc < 4; lc++) pC[lc] = exch<(1 << QA)>(pB[lc]);
#pragma unroll
    for (int lc = 0; lc < 4; lc++)
        v[lc] = cfma(f.uC, pC[lc], cfma(f.uA, pA[lc], cfma(f.uB, pB[lc], cmul(f.uS, v[lc]))));
}

// ---------- flat psi storage ----------
__device__ __forceinline__ void dumpV(const c32 v[4], c32* __restrict__ psi, int t) {
#pragma unroll
    for (int lc = 0; lc < 4; lc++) psi[(t << 2) | lc] = v[lc];
}
__device__ __forceinline__ void loadV(c32 v[4], const c32* __restrict__ psi, int t) {
#pragma unroll
    for (int lc = 0; lc < 4; lc++) v[lc] = psi[(t << 2) | lc];
}
template <int PA, int PB>
__device__ __forceinline__ void ldsApply(const F16& f, c32* __restrict__ psi, int t) {
    constexpr int PL = (PA < PB) ? PA : PB, PH = (PA < PB) ? PB : PA;
    int base = insert2(t, PL, PH);
    constexpr int oa = 1 << PA, ob = 1 << PB;
    c32 g0 = psi[base], g1 = psi[base + ob], g2 = psi[base + oa], g3 = psi[base + oa + ob];
    c32 n0 = cfma(f.u[3],  g3, cfma(f.u[2],  g2, cfma(f.u[1],  g1, cmul(f.u[0],  g0))));
    c32 n1 = cfma(f.u[7],  g3, cfma(f.u[6],  g2, cfma(f.u[5],  g1, cmul(f.u[4],  g0))));
    c32 n2 = cfma(f.u[11], g3, cfma(f.u[10], g2, cfma(f.u[9],  g1, cmul(f.u[8],  g0))));
    c32 n3 = cfma(f.u[15], g3, cfma(f.u[14], g2, cfma(f.u[13], g1, cmul(f.u[12], g0))));
    psi[base] = n0; psi[base + ob] = n1; psi[base + oa] = n2; psi[base + oa + ob] = n3;
}

__global__ __launch_bounds__(256, 1) void mega_kernel(
    const float* __restrict__ x,  const float* __restrict__ W1, const float* __restrict__ b1,
    const float* __restrict__ W2, const float* __restrict__ b2, const float* __restrict__ qp,
    const float* __restrict__ Am, const float* __restrict__ Bm, const float* __restrict__ Dm,
    float* __restrict__ out) {
    __shared__ __align__(16) c32 psiS[1024];  // MLP scratch then psi
    __shared__ c32 UeS[144];       // 9 encoding unitaries
    __shared__ c32 GpS[720];       // 45 fused pyramid gates
    __shared__ float HbS[720];     // 45 compact Hermitians: [2D0,2D1,2D2,pad, 6x(2A,2B)]
    __shared__ float encS[136];
    __shared__ float redS[180];

    const int b = blockIdx.x, t = threadIdx.x, ln = t & 63;
    float* F = (float*)psiS;  // 2048 floats of scratch

    // ================= Phase 1: MLP =================
    if (t < 128) ((float4*)F)[t] = ((const float4*)(x + (size_t)b * 512))[t];
    __syncthreads();
    {
        int q = t & 63, sl = t >> 6;
        float4 a4 = make_float4(0.f, 0.f, 0.f, 0.f);
#pragma unroll 16
        for (int kk = 0; kk < 128; kk++) {
            int k = sl * 128 + kk;
            float xk = F[k];
            const float4 w = *(const float4*)(W1 + (size_t)k * 256 + q * 4);
            a4.x = fmaf(xk, w.x, a4.x); a4.y = fmaf(xk, w.y, a4.y);
            a4.z = fmaf(xk, w.z, a4.z); a4.w = fmaf(xk, w.w, a4.w);
        }
        *(float4*)(F + 512 + sl * 256 + q * 4) = a4;
    }
    __syncthreads();
    {
        float hv = b1[t] + F[512 + t] + F[768 + t] + F[1024 + t] + F[1280 + t];
        hv = hv / (1.f + __expf(-hv));      // silu
        F[1536 + t] = hv;
    }
    __syncthreads();
    if (t < 135) {
        float a0 = b2[t], a1 = 0.f, a2 = 0.f, a3 = 0.f;
#pragma unroll 16
        for (int k = 0; k < 64; k++) {
            a0 = fmaf(F[1536 + k],       W2[(size_t)k * 135 + t],         a0);
            a1 = fmaf(F[1536 + 64 + k],  W2[(size_t)(64 + k) * 135 + t],  a1);
            a2 = fmaf(F[1536 + 128 + k], W2[(size_t)(128 + k) * 135 + t], a2);
            a3 = fmaf(F[1536 + 192 + k], W2[(size_t)(192 + k) * 135 + t], a3);
        }
        encS[t] = (a0 + a1) + (a2 + a3);
    }
    __syncthreads();

    // ========== Phase 2+3: BARRIER-FREE.  t<144: expm (in-wave swizzle) |
    //            144..188: Hb (1 obs/thread) | 192..236: prep (1 gate/thread) ==========
    if (t < 144) {
        // exp(iH) = exp(iH/64)^64, Taylor deg 7; 16 lanes per matrix, entry (i,j) per lane
        const int e = t & 15, i = e >> 2, j = e & 3;
        const int i1 = i >> 1, i2 = i & 1, j1 = j >> 1, j2 = j & 1;
        const float idq = (i == j) ? 1.f : 0.f;
        const float* th = encS + (t >> 4) * 15;
        c32 H = make_float2(0.f, 0.f);
        paccum<0,1>(H, th[0],  i1,i2,j1,j2); paccum<0,2>(H, th[1],  i1,i2,j1,j2);
        paccum<0,3>(H, th[2],  i1,i2,j1,j2); paccum<1,0>(H, th[3],  i1,i2,j1,j2);
        paccum<1,1>(H, th[4],  i1,i2,j1,j2); paccum<1,2>(H, th[5],  i1,i2,j1,j2);
        paccum<1,3>(H, th[6],  i1,i2,j1,j2); paccum<2,0>(H, th[7],  i1,i2,j1,j2);
        paccum<2,1>(H, th[8],  i1,i2,j1,j2); paccum<2,2>(H, th[9],  i1,i2,j1,j2);
        paccum<2,3>(H, th[10], i1,i2,j1,j2); paccum<3,0>(H, th[11], i1,i2,j1,j2);
        paccum<3,1>(H, th[12], i1,i2,j1,j2); paccum<3,2>(H, th[13], i1,i2,j1,j2);
        paccum<3,3>(H, th[14], i1,i2,j1,j2);
        const float sc = 1.f / 64.f;
        const c32 M = make_float2(-H.y * sc, H.x * sc);   // (i*H/64) entry
        c32 R = make_float2(idq, 0.f);
#pragma unroll 1
        for (int step = 0; step < 7; step++) {            // Horner: R <- (M*R)/(7-step) + I
            c32 acc = cmul(swzrow<0>(M), swzcol<0>(R));
            acc = cfma(swzrow<1>(M), swzcol<1>(R), acc);
            acc = cfma(swzrow<2>(M), swzcol<2>(R), acc);
            acc = cfma(swzrow<3>(M), swzcol<3>(R), acc);
            float inv = 1.f / (float)(7 - step);
            R = make_float2(fmaf(acc.x, inv, idq), acc.y * inv);
        }
#pragma unroll 1
        for (int sq = 0; sq < 6; sq++) {                  // R <- R*R
            c32 acc = cmul(swzrow<0>(R), swzcol<0>(R));
            acc = cfma(swzrow<1>(R), swzcol<1>(R), acc);
            acc = cfma(swzrow<2>(R), swzcol<2>(R), acc);
            acc = cfma(swzrow<3>(R), swzcol<3>(R), acc);
            R = acc;
        }
        UeS[t] = R;
    } else if (t < 189) {
        const int w = t - 144;
        float* Hf = HbS + w * 16;
        Hf[0] = 2.f * Dm[w * 4 + 1];
        Hf[1] = 2.f * Dm[w * 4 + 2];
        Hf[2] = 2.f * Dm[w * 4 + 3];
        Hf[3] = 0.f;
#pragma unroll
        for (int k = 0; k < 6; k++) {
            Hf[4 + 2 * k] = 2.f * Am[w * 6 + k];
            Hf[5 + 2 * k] = 2.f * Bm[w * 6 + k];
        }
    } else if (t >= 192 && t < 237) {
        const int g = t - 192;
        const float* p = qp + g * 12;
        c32 A[16], Bt[16];
        buildU3kron(A, p[0], p[1], p[2]);
        stepXX(Bt, A, p[3]);
        stepYY(A, Bt, p[4]);
        stepZZ(Bt, A, p[5]);
        stepU3(A, Bt, p[6], p[7], p[8]);
        stepXX(Bt, A, p[9]);
        stepYY(A, Bt, p[10]);
        stepZZ(Bt, A, p[11]);
#pragma unroll
        for (int k = 0; k < 16; k++) GpS[g * 16 + k] = Bt[k];
    }
    __syncthreads();

    // ================= Phase 4: state-vector simulation =================
    c32 v[4];
#pragma unroll
    for (int lc = 0; lc < 4; lc++) v[lc] = make_float2(0.f, 0.f);
    if (t == 0) v[0] = make_float2(1.f, 0.f);

    // encoding brick layer: (0,1)(2,3)(4,5)(6,7)(8,9)(1,2)(3,4)(5,6)(7,8)
    applyLL(v, loadF16(UeS + 0));
    applyL2<5, 4>(v, loadL2<5, 4>(UeS + 16, ln));
    applyL2<3, 1>(v, loadL2<3, 1>(UeS + 32, ln));
    applyL2<0, 2>(v, loadL2<0, 2>(UeS + 48, ln));
    dumpV(v, psiS, t); __syncthreads();
    ldsApply<9, 8>(loadF16(UeS + 64), psiS, t); __syncthreads();
    loadV(v, psiS, t);
    applyLoc(v, loadLoc(UeS + 80, ln));
    applyL2<4, 3>(v, loadL2<4, 3>(UeS + 96, ln));
    applyL2<1, 0>(v, loadL2<1, 0>(UeS + 112, ln));
    dumpV(v, psiS, t); __syncthreads();
    ldsApply<4, 9>(loadF16(UeS + 128), psiS, t); __syncthreads();
    loadV(v, psiS, t);

    // pyramid (fully unrolled, compile-time amax)
    {
        int g = 0;
#pragma unroll
        for (int layer = 0; layer < 9; layer++) {
            const int amax = 8 - layer;
            applyLL(v, loadF16(GpS + (g++) * 16));                               // (0,1)
            if (amax >= 1) applyLoc(v, loadLoc(GpS + (g++) * 16, ln));           // (1,2)
            if (amax >= 2) applyL2<5, 4>(v, loadL2<5, 4>(GpS + (g++) * 16, ln)); // (2,3)
            if (amax >= 3) applyL2<4, 3>(v, loadL2<4, 3>(GpS + (g++) * 16, ln)); // (3,4)
            if (amax >= 4) applyL2<3, 1>(v, loadL2<3, 1>(GpS + (g++) * 16, ln)); // (4,5)
            if (amax >= 5) applyL2<1, 0>(v, loadL2<1, 0>(GpS + (g++) * 16, ln)); // (5,6)
            if (amax >= 6) applyL2<0, 2>(v, loadL2<0, 2>(GpS + (g++) * 16, ln)); // (6,7)
            if (amax >= 7) {
                dumpV(v, psiS, t); __syncthreads();
                ldsApply<4, 9>(loadF16(GpS + (g++) * 16), psiS, t); __syncthreads();      // (7,8)
                if (amax >= 8) {
                    ldsApply<9, 8>(loadF16(GpS + (g++) * 16), psiS, t); __syncthreads();  // (8,9)
                }
                loadV(v, psiS, t);
            }
        }
    }

    // ================= Phase 5: observables (ILP x5, compact H, DPP reduce) =================
    dumpV(v, psiS, t);
    __syncthreads();
#pragma unroll
    for (int w0 = 0; w0 < NOBS; w0 += 5) {
        float pr[5];
#pragma unroll
        for (int u = 0; u < 5; u++) {
            const int w = w0 + u;
            const int pa = W2Sc[OAc[w]], pb = W2Sc[OBc[w]];
            const int pl = (pa < pb) ? pa : pb, phh = (pa < pb) ? pb : pa;
            const int oa = 1 << pa, ob = 1 << pb;
            int i0 = insert2(t, pl, phh);
            c32 vg[4];
            vg[0] = psiS[i0];      vg[1] = psiS[i0 + ob];
            vg[2] = psiS[i0 + oa]; vg[3] = psiS[i0 + oa + ob];
            const float* Hf = HbS + w * 16;
            float r = Hf[0] * fmaf(vg[0].x, vg[0].x, vg[0].y * vg[0].y)
                    + Hf[1] * fmaf(vg[1].x, vg[1].x, vg[1].y * vg[1].y)
                    + Hf[2] * fmaf(vg[2].x, vg[2].x, vg[2].y * vg[2].y);
#pragma unroll
            for (int k = 0; k < 6; k++) {
                c32 vi = vg[TIc[k]], vj = vg[TJc[k]];
                float cx = fmaf(vi.x, vj.x, vi.y * vj.y);
                float cy = fmaf(vi.x, vj.y, -vi.y * vj.x);
                r = fmaf(Hf[4 + 2 * k], cx, r);
                r = fmaf(-Hf[5 + 2 * k], cy, r);
            }
            pr[u] = wave_reduce63(r);
        }
        if (ln == 63) {
#pragma unroll
            for (int u = 0; u < 5; u++) redS[(w0 + u) * 4 + (t >> 6)] = pr[u];
        }
    }
    __syncthreads();
    if (t < NOBS)
        out[(size_t)b * NOBS + t] = redS[t * 4] + redS[t * 4 + 1] + redS[t * 4 + 2] + redS[t * 4 + 3];
}

extern "C" void kernel_launch(void* const* d_in, const int* in_sizes, int n_in,
                              void* d_out, int out_size, void* d_ws, size_t ws_size,
                              hipStream_t stream) {
    (void)in_sizes; (void)n_in; (void)out_size; (void)d_ws; (void)ws_size;
    const float* x  = (const float*)d_in[0];
    const float* W1 = (const float*)d_in[1];
    const float* b1 = (const float*)d_in[2];
    const float* W2 = (const float*)d_in[3];
    const float* b2 = (const float*)d_in[4];
    const float* qp = (const float*)d_in[5];
    const float* Am = (const float*)d_in[6];
    const float* Bm = (const float*)d_in[7];
    const float* Dm = (const float*)d_in[8];
    float* out = (float*)d_out;

    hipLaunchKernelGGL(mega_kernel, dim3(256), dim3(256), 0, stream,
                       x, W1, b1, W2, b2, qp, Am, Bm, Dm, out);
}